// Round 4
// baseline (235.862 us; speedup 1.0000x reference)
//
#include <hip/hip_runtime.h>

// FeatureVoxel4D: factorized quadlinear interpolation over 6 rank-F planes.
// planes: [F=4][193][193][C=16] float32. positions: [N,4]. out: [N,16].
//
// R4: latency-bound fix — keep float4 taps (4 lanes/point) but restore
// occupancy: two-stage-lerp bilinear (kills 24 weight VGPRs),
// __launch_bounds__(256,8) caps VGPR at 64 -> 8 waves/SIMD.

#define F_STRIDE (193 * 193 * 16)  // plane f-stride in floats
#define ROW_STRIDE (193 * 16)      // plane i-stride in floats
#define F4_F (193 * 193 * 4)       // plane f-stride in float4
#define F4_ROW (193 * 4)           // plane i-stride in float4
#define NBINS 4096

// ---- workspace layout (bytes) ----
// hist  : int[4096]    @ 0
// offs  : int[4096]    @ 16384
// key   : int[N]       @ 32768
// idx_s : int[N]       @ 32768 + 4N
// pos_s : float4[N]    @ 32768 + 8N

__device__ __forceinline__ void pos_to_base(
    float4 p4, const float* cr, const float* res,
    int& bt, int& bx, int& by, int& bz,
    float& ft, float& fx, float& fy, float& fz, bool& inr)
{
    const float lo0 = cr[0], lo1 = cr[1], lo2 = cr[2], lo3 = cr[3];
    const float hi0 = cr[4], hi1 = cr[5], hi2 = cr[6], hi3 = cr[7];
    const float r0 = res[0], r1 = res[1], r2 = res[2], r3 = res[3];

    float pt = (p4.x - lo0) / (hi0 - lo0);
    float px = (p4.y - lo1) / (hi1 - lo1);
    float py = (p4.z - lo2) / (hi2 - lo2);
    float pz = (p4.w - lo3) / (hi3 - lo3);

    inr = (pt >= 0.f) && (pt < 1.f) && (px >= 0.f) && (px < 1.f)
       && (py >= 0.f) && (py < 1.f) && (pz >= 0.f) && (pz < 1.f);

    pt *= r0; px *= r1; py *= r2; pz *= r3;

    bt = min(max((int)floorf(pt), 0), (int)r0 - 1);
    bx = min(max((int)floorf(px), 0), (int)r1 - 1);
    by = min(max((int)floorf(py), 0), (int)r2 - 1);
    bz = min(max((int)floorf(pz), 0), (int)r3 - 1);

    ft = pt - (float)bt; fx = px - (float)bx;
    fy = py - (float)by; fz = pz - (float)bz;
}

__device__ __forceinline__ int morton4d(int a, int b, int c, int d) {
    int m = 0;
#pragma unroll
    for (int i = 0; i < 3; ++i) {
        m |= ((d >> i) & 1) << (4 * i + 0);
        m |= ((c >> i) & 1) << (4 * i + 1);
        m |= ((b >> i) & 1) << (4 * i + 2);
        m |= ((a >> i) & 1) << (4 * i + 3);
    }
    return m;
}

__global__ __launch_bounds__(256) void k_hist(
    const float* __restrict__ pos, const float* __restrict__ cr,
    const float* __restrict__ res, int* __restrict__ key,
    int* __restrict__ hist, int N)
{
    const int i = blockIdx.x * 256 + threadIdx.x;
    if (i >= N) return;
    const float4 p4 = *reinterpret_cast<const float4*>(pos + (size_t)i * 4);
    int bt, bx, by, bz; float ft, fx, fy, fz; bool inr;
    pos_to_base(p4, cr, res, bt, bx, by, bz, ft, fx, fy, fz, inr);
    const int b = morton4d(bt / 24, bx / 24, by / 24, bz / 24);
    key[i] = b;
    atomicAdd(&hist[b], 1);
}

__global__ __launch_bounds__(256) void k_scan(const int* __restrict__ hist,
                                              int* __restrict__ offs)
{
    __shared__ int part[256];
    const int t = threadIdx.x;
    int loc[16];
    int s = 0;
    const int base = t * 16;
#pragma unroll
    for (int j = 0; j < 16; ++j) { loc[j] = s; s += hist[base + j]; }
    part[t] = s;
    __syncthreads();
    for (int d = 1; d < 256; d <<= 1) {
        int v = (t >= d) ? part[t - d] : 0;
        __syncthreads();
        part[t] += v;
        __syncthreads();
    }
    const int excl = (t == 0) ? 0 : part[t - 1];
#pragma unroll
    for (int j = 0; j < 16; ++j) offs[base + j] = excl + loc[j];
}

__global__ __launch_bounds__(256) void k_scatter(
    const float* __restrict__ pos, const int* __restrict__ key,
    int* __restrict__ offs, float4* __restrict__ pos_s,
    int* __restrict__ idx_s, int N)
{
    const int i = blockIdx.x * 256 + threadIdx.x;
    if (i >= N) return;
    const int b = key[i];
    const int o = atomicAdd(&offs[b], 1);
    pos_s[o] = *reinterpret_cast<const float4*>(pos + (size_t)i * 4);
    idx_s[o] = i;
}

// two-stage-lerp bilinear: needs only fi, fj (no precomputed corner weights)
__device__ __forceinline__ float4 bil4(const float4* __restrict__ p, int o,
                                       float fi, float fj)
{
    const float4 v00 = p[o];
    const float4 v01 = p[o + 4];
    const float4 v10 = p[o + F4_ROW];
    const float4 v11 = p[o + F4_ROW + 4];
    float4 a, b, r;
    a.x = v00.x + fj * (v01.x - v00.x);
    a.y = v00.y + fj * (v01.y - v00.y);
    a.z = v00.z + fj * (v01.z - v00.z);
    a.w = v00.w + fj * (v01.w - v00.w);
    b.x = v10.x + fj * (v11.x - v10.x);
    b.y = v10.y + fj * (v11.y - v10.y);
    b.z = v10.z + fj * (v11.z - v10.z);
    b.w = v10.w + fj * (v11.w - v10.w);
    r.x = a.x + fi * (b.x - a.x);
    r.y = a.y + fi * (b.y - a.y);
    r.z = a.z + fi * (b.z - a.z);
    r.w = a.w + fi * (b.w - a.w);
    return r;
}

__global__ __launch_bounds__(256, 8) void fv4d_sorted(
    const float4* __restrict__ pos_s,
    const int* __restrict__ idx_s,
    const float4* __restrict__ ptx,
    const float4* __restrict__ pty,
    const float4* __restrict__ ptz,
    const float4* __restrict__ pxy,
    const float4* __restrict__ pxz,
    const float4* __restrict__ pyz,
    const float* __restrict__ cr,
    const float* __restrict__ res,
    float4* __restrict__ out,
    int N)
{
    // bijective XCD-chunked swizzle (m204)
    const int nwg = gridDim.x;
    const int q = nwg >> 3, r = nwg & 7;
    const int xcd = blockIdx.x & 7, j = blockIdx.x >> 3;
    const int sb = (xcd < r ? xcd * (q + 1) : r * (q + 1) + (xcd - r) * q) + j;

    const int n = sb * 64 + (threadIdx.x >> 2);   // 4 lanes per point
    const int q4 = threadIdx.x & 3;               // channel quad 0..3
    if (n >= N) return;

    const float4 p4 = pos_s[n];
    int bt, bx, by, bz; float ft, fx, fy, fz; bool inr;
    pos_to_base(p4, cr, res, bt, bx, by, bz, ft, fx, fy, fz, inr);

    // base offsets in float4 units, channel quad q4
    const int otx = (bt * 193 + bx) * 4 + q4;
    const int oyz = (by * 193 + bz) * 4 + q4;
    const int oty = (bt * 193 + by) * 4 + q4;
    const int oxz = (bx * 193 + bz) * 4 + q4;
    const int otz = (bt * 193 + bz) * 4 + q4;
    const int oxy = (bx * 193 + by) * 4 + q4;

    float4 acc = make_float4(0.f, 0.f, 0.f, 0.f);
#pragma unroll
    for (int f = 0; f < 4; ++f) {
        const int fo = f * F4_F;
        const float4 atx = bil4(ptx, fo + otx, ft, fx);
        const float4 ayz = bil4(pyz, fo + oyz, fy, fz);
        const float4 aty = bil4(pty, fo + oty, ft, fy);
        const float4 axz = bil4(pxz, fo + oxz, fx, fz);
        const float4 atz = bil4(ptz, fo + otz, ft, fz);
        const float4 axy = bil4(pxy, fo + oxy, fx, fy);
        acc.x += atx.x * ayz.x + aty.x * axz.x + atz.x * axy.x;
        acc.y += atx.y * ayz.y + aty.y * axz.y + atz.y * axy.y;
        acc.z += atx.z * ayz.z + aty.z * axz.z + atz.z * axy.z;
        acc.w += atx.w * ayz.w + aty.w * axz.w + atz.w * axy.w;
    }

    if (!inr) acc = make_float4(0.f, 0.f, 0.f, 0.f);
    const int orig = idx_s[n];
    out[(size_t)orig * 4 + q4] = acc;
}

// fallback (unsorted, scalar) kernel, used only if ws_size is too small
__global__ __launch_bounds__(256) void fv4d_plain(
    const float* __restrict__ pos,
    const float* __restrict__ ptx, const float* __restrict__ pty,
    const float* __restrict__ ptz, const float* __restrict__ pxy,
    const float* __restrict__ pxz, const float* __restrict__ pyz,
    const float* __restrict__ cr, const float* __restrict__ res,
    float* __restrict__ out, int N)
{
    const int g = blockIdx.x * 256 + threadIdx.x;
    const int n = g >> 4;
    const int c = g & 15;
    if (n >= N) return;
    const float4 p4 = *reinterpret_cast<const float4*>(pos + (size_t)n * 4);
    int bt, bx, by, bz; float ft, fx, fy, fz; bool inr;
    pos_to_base(p4, cr, res, bt, bx, by, bz, ft, fx, fy, fz, inr);
    const float gt = 1.f - ft, gx = 1.f - fx, gy = 1.f - fy, gz = 1.f - fz;
    const float wtx00 = gt * gx, wtx01 = gt * fx, wtx10 = ft * gx, wtx11 = ft * fx;
    const float wyz00 = gy * gz, wyz01 = gy * fz, wyz10 = fy * gz, wyz11 = fy * fz;
    const float wty00 = gt * gy, wty01 = gt * fy, wty10 = ft * gy, wty11 = ft * fy;
    const float wxz00 = gx * gz, wxz01 = gx * fz, wxz10 = fx * gz, wxz11 = fx * fz;
    const float wtz00 = gt * gz, wtz01 = gt * fz, wtz10 = ft * gz, wtz11 = ft * fz;
    const float wxy00 = gx * gy, wxy01 = gx * fy, wxy10 = fx * gy, wxy11 = fx * fy;
    const int otx = (bt * 193 + bx) * 16 + c;
    const int oyz = (by * 193 + bz) * 16 + c;
    const int oty = (bt * 193 + by) * 16 + c;
    const int oxz = (bx * 193 + bz) * 16 + c;
    const int otz = (bt * 193 + bz) * 16 + c;
    const int oxy = (bx * 193 + by) * 16 + c;
    float acc = 0.f;
#pragma unroll
    for (int f = 0; f < 4; ++f) {
        const int fo = f * F_STRIDE;
        acc += (ptx[fo + otx] * wtx00 + ptx[fo + otx + 16] * wtx01
              + ptx[fo + otx + ROW_STRIDE] * wtx10 + ptx[fo + otx + ROW_STRIDE + 16] * wtx11)
             * (pyz[fo + oyz] * wyz00 + pyz[fo + oyz + 16] * wyz01
              + pyz[fo + oyz + ROW_STRIDE] * wyz10 + pyz[fo + oyz + ROW_STRIDE + 16] * wyz11)
             + (pty[fo + oty] * wty00 + pty[fo + oty + 16] * wty01
              + pty[fo + oty + ROW_STRIDE] * wty10 + pty[fo + oty + ROW_STRIDE + 16] * wty11)
             * (pxz[fo + oxz] * wxz00 + pxz[fo + oxz + 16] * wxz01
              + pxz[fo + oxz + ROW_STRIDE] * wxz10 + pxz[fo + oxz + ROW_STRIDE + 16] * wxz11)
             + (ptz[fo + otz] * wtz00 + ptz[fo + otz + 16] * wtz01
              + ptz[fo + otz + ROW_STRIDE] * wtz10 + ptz[fo + otz + ROW_STRIDE + 16] * wtz11)
             * (pxy[fo + oxy] * wxy00 + pxy[fo + oxy + 16] * wxy01
              + pxy[fo + oxy + ROW_STRIDE] * wxy10 + pxy[fo + oxy + ROW_STRIDE + 16] * wxy11);
    }
    out[(size_t)n * 16 + c] = inr ? acc : 0.f;
}

extern "C" void kernel_launch(void* const* d_in, const int* in_sizes, int n_in,
                              void* d_out, int out_size, void* d_ws, size_t ws_size,
                              hipStream_t stream) {
    const float* pos = (const float*)d_in[0];
    const float* ptx = (const float*)d_in[1];
    const float* pty = (const float*)d_in[2];
    const float* ptz = (const float*)d_in[3];
    const float* pxy = (const float*)d_in[4];
    const float* pxz = (const float*)d_in[5];
    const float* pyz = (const float*)d_in[6];
    const float* cr  = (const float*)d_in[7];
    const float* res = (const float*)d_in[8];
    float* out = (float*)d_out;

    const int N = in_sizes[0] / 4;
    const size_t need = 32768 + (size_t)8 * N + (size_t)16 * N;

    if (ws_size < need) {
        const int blocks = (N * 16 + 255) / 256;
        fv4d_plain<<<blocks, 256, 0, stream>>>(pos, ptx, pty, ptz, pxy, pxz, pyz,
                                               cr, res, out, N);
        return;
    }

    char* ws = (char*)d_ws;
    int*    hist  = (int*)(ws);
    int*    offs  = (int*)(ws + 16384);
    int*    key   = (int*)(ws + 32768);
    int*    idx_s = (int*)(ws + 32768 + (size_t)4 * N);
    float4* pos_s = (float4*)(ws + 32768 + (size_t)8 * N);

    const int pb = (N + 255) / 256;
    hipMemsetAsync(hist, 0, NBINS * sizeof(int), stream);
    k_hist<<<pb, 256, 0, stream>>>(pos, cr, res, key, hist, N);
    k_scan<<<1, 256, 0, stream>>>(hist, offs);
    k_scatter<<<pb, 256, 0, stream>>>(pos, key, offs, pos_s, idx_s, N);

    const int blocks = (N + 63) / 64;  // 64 points per block (4 lanes/point)
    fv4d_sorted<<<blocks, 256, 0, stream>>>(
        pos_s, idx_s,
        (const float4*)ptx, (const float4*)pty, (const float4*)ptz,
        (const float4*)pxy, (const float4*)pxz, (const float4*)pyz,
        cr, res, (float4*)out, N);
}

// Round 5
// 109.083 us; speedup vs baseline: 2.1622x; 2.1622x over previous
//
#include <hip/hip_runtime.h>
#include <hip/hip_fp16.h>

// FeatureVoxel4D: factorized quadlinear interpolation over 6 rank-F planes.
// planes: [F=4][193][193][C=16] float32. positions: [N,4]. out: [N,16].
//
// R5: miss-byte reduction. Planes converted per-call to fp16 packed
// [node][c][f] (128 B/node = all 4 f-slices), halving the gather working set
// (57 -> 28.6 MB; per-XCD Morton chunk now ~fits 4 MB L2) and halving
// line-touches per point. Sort (Morton counting sort) kept from R2/R3.
// NO __launch_bounds__ occupancy cap (R4 lesson: caused scratch spills).

#define F_STRIDE (193 * 193 * 16)  // f32 plane f-stride in floats
#define ROW_STRIDE (193 * 16)
#define F4_F (193 * 193 * 4)       // f32 plane f-stride in float4
#define F4_ROW (193 * 4)
#define NBINS 4096
#define NODES (193 * 193)             // 37249
#define PH (NODES * 64)               // halves per packed plane
#define PB ((size_t)PH * 2)           // bytes per packed plane (4,767,872)
#define CONV_ELEMS (NODES * 16)       // 595984 (node,c) pairs per plane
#define NCB ((CONV_ELEMS + 255) / 256)  // 2329 convert blocks per plane

// ---- full-path workspace layout (bytes) ----
// qplanes : fp16 packed, 6*PB            @ 0            (28,607,232)
// hist    : int[4096]                    @ 6*PB
// offs    : int[4096]                    @ 6*PB + 16384
// key     : int[N]                       @ 6*PB + 32768
// idx_s   : int[N]                       @ ... + 4N
// pos_s   : float4[N]                    @ ... + 8N     (16B aligned)

__device__ __forceinline__ void pos_to_base(
    float4 p4, const float* cr, const float* res,
    int& bt, int& bx, int& by, int& bz,
    float& ft, float& fx, float& fy, float& fz, bool& inr)
{
    const float lo0 = cr[0], lo1 = cr[1], lo2 = cr[2], lo3 = cr[3];
    const float hi0 = cr[4], hi1 = cr[5], hi2 = cr[6], hi3 = cr[7];
    const float r0 = res[0], r1 = res[1], r2 = res[2], r3 = res[3];

    float pt = (p4.x - lo0) / (hi0 - lo0);
    float px = (p4.y - lo1) / (hi1 - lo1);
    float py = (p4.z - lo2) / (hi2 - lo2);
    float pz = (p4.w - lo3) / (hi3 - lo3);

    inr = (pt >= 0.f) && (pt < 1.f) && (px >= 0.f) && (px < 1.f)
       && (py >= 0.f) && (py < 1.f) && (pz >= 0.f) && (pz < 1.f);

    pt *= r0; px *= r1; py *= r2; pz *= r3;

    bt = min(max((int)floorf(pt), 0), (int)r0 - 1);
    bx = min(max((int)floorf(px), 0), (int)r1 - 1);
    by = min(max((int)floorf(py), 0), (int)r2 - 1);
    bz = min(max((int)floorf(pz), 0), (int)r3 - 1);

    ft = pt - (float)bt; fx = px - (float)bx;
    fy = py - (float)by; fz = pz - (float)bz;
}

__device__ __forceinline__ int morton4d(int a, int b, int c, int d) {
    int m = 0;
#pragma unroll
    for (int i = 0; i < 3; ++i) {
        m |= ((d >> i) & 1) << (4 * i + 0);
        m |= ((c >> i) & 1) << (4 * i + 1);
        m |= ((b >> i) & 1) << (4 * i + 2);
        m |= ((a >> i) & 1) << (4 * i + 3);
    }
    return m;
}

// ---- fused convert (f32 -> packed fp16) + histogram ----
__global__ __launch_bounds__(256) void k_convert_hist(
    const float* __restrict__ ptx, const float* __restrict__ pty,
    const float* __restrict__ ptz, const float* __restrict__ pxy,
    const float* __restrict__ pxz, const float* __restrict__ pyz,
    __half* __restrict__ qplanes,
    const float* __restrict__ pos, const float* __restrict__ cr,
    const float* __restrict__ res, int* __restrict__ key,
    int* __restrict__ hist, int N)
{
    const int b = blockIdx.x;
    if (b < 6 * NCB) {
        const int plane = b / NCB;
        const int idx = (b % NCB) * 256 + threadIdx.x;
        if (idx >= CONV_ELEMS) return;
        const float* src = plane == 0 ? ptx : plane == 1 ? pty : plane == 2 ? ptz
                         : plane == 3 ? pxy : plane == 4 ? pxz : pyz;
        const int c = idx & 15, node = idx >> 4;
        const int o = node * 16 + c;
        const float v0 = src[o];
        const float v1 = src[o + F_STRIDE];
        const float v2 = src[o + 2 * F_STRIDE];
        const float v3 = src[o + 3 * F_STRIDE];
        const __half2 h01 = __floats2half2_rn(v0, v1);
        const __half2 h23 = __floats2half2_rn(v2, v3);
        uint2 w;
        w.x = *(const unsigned*)&h01;
        w.y = *(const unsigned*)&h23;
        *(uint2*)(qplanes + (size_t)plane * PH + node * 64 + c * 4) = w;
    } else {
        const int i = (b - 6 * NCB) * 256 + threadIdx.x;
        if (i >= N) return;
        const float4 p4 = *reinterpret_cast<const float4*>(pos + (size_t)i * 4);
        int bt, bx, by, bz; float ft, fx, fy, fz; bool inr;
        pos_to_base(p4, cr, res, bt, bx, by, bz, ft, fx, fy, fz, inr);
        const int k = morton4d(bt / 24, bx / 24, by / 24, bz / 24);
        key[i] = k;
        atomicAdd(&hist[k], 1);
    }
}

__global__ __launch_bounds__(256) void k_scan(const int* __restrict__ hist,
                                              int* __restrict__ offs)
{
    __shared__ int part[256];
    const int t = threadIdx.x;
    int loc[16];
    int s = 0;
    const int base = t * 16;
#pragma unroll
    for (int j = 0; j < 16; ++j) { loc[j] = s; s += hist[base + j]; }
    part[t] = s;
    __syncthreads();
    for (int d = 1; d < 256; d <<= 1) {
        int v = (t >= d) ? part[t - d] : 0;
        __syncthreads();
        part[t] += v;
        __syncthreads();
    }
    const int excl = (t == 0) ? 0 : part[t - 1];
#pragma unroll
    for (int j = 0; j < 16; ++j) offs[base + j] = excl + loc[j];
}

__global__ __launch_bounds__(256) void k_scatter(
    const float* __restrict__ pos, const int* __restrict__ key,
    int* __restrict__ offs, float4* __restrict__ pos_s,
    int* __restrict__ idx_s, int N)
{
    const int i = blockIdx.x * 256 + threadIdx.x;
    if (i >= N) return;
    const int b = key[i];
    const int o = atomicAdd(&offs[b], 1);
    pos_s[o] = *reinterpret_cast<const float4*>(pos + (size_t)i * 4);
    idx_s[o] = i;
}

// accumulate w * (16 fp16 halves packed in two uint4) into af[16]
__device__ __forceinline__ void fma16(uint4 a, uint4 b, float w, float* af) {
    const unsigned u[8] = {a.x, a.y, a.z, a.w, b.x, b.y, b.z, b.w};
#pragma unroll
    for (int k = 0; k < 8; ++k) {
        af[2 * k]     += w * __half2float(__ushort_as_half((unsigned short)(u[k] & 0xffffu)));
        af[2 * k + 1] += w * __half2float(__ushort_as_half((unsigned short)(u[k] >> 16)));
    }
}

// bilerp of one node-quad: p00 points at this lane's 32B (c-quad x 4f) chunk
__device__ __forceinline__ void bilerp16(const __half* __restrict__ p00,
                                         float fi, float fj, float* af)
{
    const uint4 a00 = ((const uint4*)p00)[0];
    const uint4 b00 = ((const uint4*)p00)[1];
    const uint4 a01 = ((const uint4*)(p00 + 64))[0];
    const uint4 b01 = ((const uint4*)(p00 + 64))[1];
    const uint4 a10 = ((const uint4*)(p00 + 193 * 64))[0];
    const uint4 b10 = ((const uint4*)(p00 + 193 * 64))[1];
    const uint4 a11 = ((const uint4*)(p00 + 193 * 64 + 64))[0];
    const uint4 b11 = ((const uint4*)(p00 + 193 * 64 + 64))[1];
    const float w11 = fi * fj;
    const float w10 = fi - w11;
    const float w01 = fj - w11;
    const float w00 = 1.f - fi - fj + w11;
#pragma unroll
    for (int k = 0; k < 16; ++k) af[k] = 0.f;
    fma16(a00, b00, w00, af);
    fma16(a01, b01, w01, af);
    fma16(a10, b10, w10, af);
    fma16(a11, b11, w11, af);
}

__global__ __launch_bounds__(256) void fv4d_fp16(
    const float4* __restrict__ pos_s, const int* __restrict__ idx_s,
    const __half* __restrict__ qplanes, const float* __restrict__ cr,
    const float* __restrict__ res, float4* __restrict__ out, int N)
{
    // bijective XCD-chunked swizzle (m204)
    const int nwg = gridDim.x;
    const int q = nwg >> 3, r = nwg & 7;
    const int xcd = blockIdx.x & 7, jj = blockIdx.x >> 3;
    const int sb = (xcd < r ? xcd * (q + 1) : r * (q + 1) + (xcd - r) * q) + jj;

    const int n = sb * 64 + (threadIdx.x >> 2);  // 4 lanes per point
    const int q4 = threadIdx.x & 3;              // channel quad
    if (n >= N) return;

    const float4 p4 = pos_s[n];
    int bt, bx, by, bz; float ft, fx, fy, fz; bool inr;
    pos_to_base(p4, cr, res, bt, bx, by, bz, ft, fx, fy, fz, inr);

    const __half* qtx = qplanes;
    const __half* qty = qplanes + PH;
    const __half* qtz = qplanes + 2 * (size_t)PH;
    const __half* qxy = qplanes + 3 * (size_t)PH;
    const __half* qxz = qplanes + 4 * (size_t)PH;
    const __half* qyz = qplanes + 5 * (size_t)PH;
    const int co = q4 * 16;  // halves offset of this lane's c-quad

    float acc0 = 0.f, acc1 = 0.f, acc2 = 0.f, acc3 = 0.f;
    float af[16], bf[16];

    // pair 0: tx(t,x) * yz(y,z)
    bilerp16(qtx + (bt * 193 + bx) * 64 + co, ft, fx, af);
    bilerp16(qyz + (by * 193 + bz) * 64 + co, fy, fz, bf);
#pragma unroll
    for (int f = 0; f < 4; ++f) {
        acc0 += af[f] * bf[f];
        acc1 += af[4 + f] * bf[4 + f];
        acc2 += af[8 + f] * bf[8 + f];
        acc3 += af[12 + f] * bf[12 + f];
    }
    // pair 1: ty(t,y) * xz(x,z)
    bilerp16(qty + (bt * 193 + by) * 64 + co, ft, fy, af);
    bilerp16(qxz + (bx * 193 + bz) * 64 + co, fx, fz, bf);
#pragma unroll
    for (int f = 0; f < 4; ++f) {
        acc0 += af[f] * bf[f];
        acc1 += af[4 + f] * bf[4 + f];
        acc2 += af[8 + f] * bf[8 + f];
        acc3 += af[12 + f] * bf[12 + f];
    }
    // pair 2: tz(t,z) * xy(x,y)
    bilerp16(qtz + (bt * 193 + bz) * 64 + co, ft, fz, af);
    bilerp16(qxy + (bx * 193 + by) * 64 + co, fx, fy, bf);
#pragma unroll
    for (int f = 0; f < 4; ++f) {
        acc0 += af[f] * bf[f];
        acc1 += af[4 + f] * bf[4 + f];
        acc2 += af[8 + f] * bf[8 + f];
        acc3 += af[12 + f] * bf[12 + f];
    }

    float4 o;
    o.x = inr ? acc0 : 0.f;
    o.y = inr ? acc1 : 0.f;
    o.z = inr ? acc2 : 0.f;
    o.w = inr ? acc3 : 0.f;
    out[(size_t)idx_s[n] * 4 + q4] = o;
}

// ---- mid-tier fallback: R3 float4 sorted kernel (f32 planes) ----
__device__ __forceinline__ float4 bil4(const float4* __restrict__ p, int o,
                                       float fi, float fj)
{
    const float4 v00 = p[o];
    const float4 v01 = p[o + 4];
    const float4 v10 = p[o + F4_ROW];
    const float4 v11 = p[o + F4_ROW + 4];
    float4 a, b, r;
    a.x = v00.x + fj * (v01.x - v00.x);
    a.y = v00.y + fj * (v01.y - v00.y);
    a.z = v00.z + fj * (v01.z - v00.z);
    a.w = v00.w + fj * (v01.w - v00.w);
    b.x = v10.x + fj * (v11.x - v10.x);
    b.y = v10.y + fj * (v11.y - v10.y);
    b.z = v10.z + fj * (v11.z - v10.z);
    b.w = v10.w + fj * (v11.w - v10.w);
    r.x = a.x + fi * (b.x - a.x);
    r.y = a.y + fi * (b.y - a.y);
    r.z = a.z + fi * (b.z - a.z);
    r.w = a.w + fi * (b.w - a.w);
    return r;
}

__global__ __launch_bounds__(256) void fv4d_sorted(
    const float4* __restrict__ pos_s, const int* __restrict__ idx_s,
    const float4* __restrict__ ptx, const float4* __restrict__ pty,
    const float4* __restrict__ ptz, const float4* __restrict__ pxy,
    const float4* __restrict__ pxz, const float4* __restrict__ pyz,
    const float* __restrict__ cr, const float* __restrict__ res,
    float4* __restrict__ out, int N)
{
    const int nwg = gridDim.x;
    const int q = nwg >> 3, r = nwg & 7;
    const int xcd = blockIdx.x & 7, jj = blockIdx.x >> 3;
    const int sb = (xcd < r ? xcd * (q + 1) : r * (q + 1) + (xcd - r) * q) + jj;

    const int n = sb * 64 + (threadIdx.x >> 2);
    const int q4 = threadIdx.x & 3;
    if (n >= N) return;

    const float4 p4 = pos_s[n];
    int bt, bx, by, bz; float ft, fx, fy, fz; bool inr;
    pos_to_base(p4, cr, res, bt, bx, by, bz, ft, fx, fy, fz, inr);

    const int otx = (bt * 193 + bx) * 4 + q4;
    const int oyz = (by * 193 + bz) * 4 + q4;
    const int oty = (bt * 193 + by) * 4 + q4;
    const int oxz = (bx * 193 + bz) * 4 + q4;
    const int otz = (bt * 193 + bz) * 4 + q4;
    const int oxy = (bx * 193 + by) * 4 + q4;

    float4 acc = make_float4(0.f, 0.f, 0.f, 0.f);
#pragma unroll
    for (int f = 0; f < 4; ++f) {
        const int fo = f * F4_F;
        const float4 atx = bil4(ptx, fo + otx, ft, fx);
        const float4 ayz = bil4(pyz, fo + oyz, fy, fz);
        const float4 aty = bil4(pty, fo + oty, ft, fy);
        const float4 axz = bil4(pxz, fo + oxz, fx, fz);
        const float4 atz = bil4(ptz, fo + otz, ft, fz);
        const float4 axy = bil4(pxy, fo + oxy, fx, fy);
        acc.x += atx.x * ayz.x + aty.x * axz.x + atz.x * axy.x;
        acc.y += atx.y * ayz.y + aty.y * axz.y + atz.y * axy.y;
        acc.z += atx.z * ayz.z + aty.z * axz.z + atz.z * axy.z;
        acc.w += atx.w * ayz.w + aty.w * axz.w + atz.w * axy.w;
    }

    if (!inr) acc = make_float4(0.f, 0.f, 0.f, 0.f);
    out[(size_t)idx_s[n] * 4 + q4] = acc;
}

__global__ __launch_bounds__(256) void k_hist(
    const float* __restrict__ pos, const float* __restrict__ cr,
    const float* __restrict__ res, int* __restrict__ key,
    int* __restrict__ hist, int N)
{
    const int i = blockIdx.x * 256 + threadIdx.x;
    if (i >= N) return;
    const float4 p4 = *reinterpret_cast<const float4*>(pos + (size_t)i * 4);
    int bt, bx, by, bz; float ft, fx, fy, fz; bool inr;
    pos_to_base(p4, cr, res, bt, bx, by, bz, ft, fx, fy, fz, inr);
    const int b = morton4d(bt / 24, bx / 24, by / 24, bz / 24);
    key[i] = b;
    atomicAdd(&hist[b], 1);
}

// bottom-tier fallback: plain scalar kernel
__global__ __launch_bounds__(256) void fv4d_plain(
    const float* __restrict__ pos,
    const float* __restrict__ ptx, const float* __restrict__ pty,
    const float* __restrict__ ptz, const float* __restrict__ pxy,
    const float* __restrict__ pxz, const float* __restrict__ pyz,
    const float* __restrict__ cr, const float* __restrict__ res,
    float* __restrict__ out, int N)
{
    const int g = blockIdx.x * 256 + threadIdx.x;
    const int n = g >> 4;
    const int c = g & 15;
    if (n >= N) return;
    const float4 p4 = *reinterpret_cast<const float4*>(pos + (size_t)n * 4);
    int bt, bx, by, bz; float ft, fx, fy, fz; bool inr;
    pos_to_base(p4, cr, res, bt, bx, by, bz, ft, fx, fy, fz, inr);
    const float gt = 1.f - ft, gx = 1.f - fx, gy = 1.f - fy, gz = 1.f - fz;
    const float wtx00 = gt * gx, wtx01 = gt * fx, wtx10 = ft * gx, wtx11 = ft * fx;
    const float wyz00 = gy * gz, wyz01 = gy * fz, wyz10 = fy * gz, wyz11 = fy * fz;
    const float wty00 = gt * gy, wty01 = gt * fy, wty10 = ft * gy, wty11 = ft * fy;
    const float wxz00 = gx * gz, wxz01 = gx * fz, wxz10 = fx * gz, wxz11 = fx * fz;
    const float wtz00 = gt * gz, wtz01 = gt * fz, wtz10 = ft * gz, wtz11 = ft * fz;
    const float wxy00 = gx * gy, wxy01 = gx * fy, wxy10 = fx * gy, wxy11 = fx * fy;
    const int otx = (bt * 193 + bx) * 16 + c;
    const int oyz = (by * 193 + bz) * 16 + c;
    const int oty = (bt * 193 + by) * 16 + c;
    const int oxz = (bx * 193 + bz) * 16 + c;
    const int otz = (bt * 193 + bz) * 16 + c;
    const int oxy = (bx * 193 + by) * 16 + c;
    float acc = 0.f;
#pragma unroll
    for (int f = 0; f < 4; ++f) {
        const int fo = f * F_STRIDE;
        acc += (ptx[fo + otx] * wtx00 + ptx[fo + otx + 16] * wtx01
              + ptx[fo + otx + ROW_STRIDE] * wtx10 + ptx[fo + otx + ROW_STRIDE + 16] * wtx11)
             * (pyz[fo + oyz] * wyz00 + pyz[fo + oyz + 16] * wyz01
              + pyz[fo + oyz + ROW_STRIDE] * wyz10 + pyz[fo + oyz + ROW_STRIDE + 16] * wyz11)
             + (pty[fo + oty] * wty00 + pty[fo + oty + 16] * wty01
              + pty[fo + oty + ROW_STRIDE] * wty10 + pty[fo + oty + ROW_STRIDE + 16] * wty11)
             * (pxz[fo + oxz] * wxz00 + pxz[fo + oxz + 16] * wxz01
              + pxz[fo + oxz + ROW_STRIDE] * wxz10 + pxz[fo + oxz + ROW_STRIDE + 16] * wxz11)
             + (ptz[fo + otz] * wtz00 + ptz[fo + otz + 16] * wtz01
              + ptz[fo + otz + ROW_STRIDE] * wtz10 + ptz[fo + otz + ROW_STRIDE + 16] * wtz11)
             * (pxy[fo + oxy] * wxy00 + pxy[fo + oxy + 16] * wxy01
              + pxy[fo + oxy + ROW_STRIDE] * wxy10 + pxy[fo + oxy + ROW_STRIDE + 16] * wxy11);
    }
    out[(size_t)n * 16 + c] = inr ? acc : 0.f;
}

extern "C" void kernel_launch(void* const* d_in, const int* in_sizes, int n_in,
                              void* d_out, int out_size, void* d_ws, size_t ws_size,
                              hipStream_t stream) {
    const float* pos = (const float*)d_in[0];
    const float* ptx = (const float*)d_in[1];
    const float* pty = (const float*)d_in[2];
    const float* ptz = (const float*)d_in[3];
    const float* pxy = (const float*)d_in[4];
    const float* pxz = (const float*)d_in[5];
    const float* pyz = (const float*)d_in[6];
    const float* cr  = (const float*)d_in[7];
    const float* res = (const float*)d_in[8];
    float* out = (float*)d_out;

    const int N = in_sizes[0] / 4;
    const int pb = (N + 255) / 256;
    const int mainBlocks = (N + 63) / 64;

    const size_t QTOT = 6 * PB;                       // 28,607,232
    const size_t full_need = QTOT + 32768 + (size_t)24 * N;
    const size_t sort_need = 32768 + (size_t)24 * N;

    if (ws_size >= full_need) {
        char* ws = (char*)d_ws;
        __half* qplanes = (__half*)ws;
        int*    hist    = (int*)(ws + QTOT);
        int*    offs    = (int*)(ws + QTOT + 16384);
        int*    key     = (int*)(ws + QTOT + 32768);
        int*    idx_s   = (int*)(ws + QTOT + 32768 + (size_t)4 * N);
        float4* pos_s   = (float4*)(ws + QTOT + 32768 + (size_t)8 * N);

        hipMemsetAsync(hist, 0, NBINS * sizeof(int), stream);
        k_convert_hist<<<6 * NCB + pb, 256, 0, stream>>>(
            ptx, pty, ptz, pxy, pxz, pyz, qplanes, pos, cr, res, key, hist, N);
        k_scan<<<1, 256, 0, stream>>>(hist, offs);
        k_scatter<<<pb, 256, 0, stream>>>(pos, key, offs, pos_s, idx_s, N);
        fv4d_fp16<<<mainBlocks, 256, 0, stream>>>(pos_s, idx_s, qplanes, cr, res,
                                                  (float4*)out, N);
    } else if (ws_size >= sort_need) {
        char* ws = (char*)d_ws;
        int*    hist  = (int*)(ws);
        int*    offs  = (int*)(ws + 16384);
        int*    key   = (int*)(ws + 32768);
        int*    idx_s = (int*)(ws + 32768 + (size_t)4 * N);
        float4* pos_s = (float4*)(ws + 32768 + (size_t)8 * N);

        hipMemsetAsync(hist, 0, NBINS * sizeof(int), stream);
        k_hist<<<pb, 256, 0, stream>>>(pos, cr, res, key, hist, N);
        k_scan<<<1, 256, 0, stream>>>(hist, offs);
        k_scatter<<<pb, 256, 0, stream>>>(pos, key, offs, pos_s, idx_s, N);
        fv4d_sorted<<<mainBlocks, 256, 0, stream>>>(
            pos_s, idx_s,
            (const float4*)ptx, (const float4*)pty, (const float4*)ptz,
            (const float4*)pxy, (const float4*)pxz, (const float4*)pyz,
            cr, res, (float4*)out, N);
    } else {
        const int blocks = (N * 16 + 255) / 256;
        fv4d_plain<<<blocks, 256, 0, stream>>>(pos, ptx, pty, ptz, pxy, pxz, pyz,
                                               cr, res, out, N);
    }
}

// Round 6
// 94.037 us; speedup vs baseline: 2.5082x; 1.1600x over previous
//
#include <hip/hip_runtime.h>
#include <hip/hip_fp16.h>

// FeatureVoxel4D: factorized quadlinear interpolation over 6 rank-F planes.
// planes: [F=4][193][193][C=16] float32. positions: [N,4]. out: [N,16].
//
// R6: 8 lanes/point (one uint4 = 2 channels x 4 f per tap) -> halves
// per-thread load count & register pressure, doubles thread-level
// parallelism for the latency-bound gather. fp16 packed planes + Morton
// counting sort + XCD swizzle kept from R5.

#define F_STRIDE (193 * 193 * 16)  // f32 plane f-stride in floats
#define ROW_STRIDE (193 * 16)
#define F4_F (193 * 193 * 4)       // f32 plane f-stride in float4
#define F4_ROW (193 * 4)
#define NBINS 4096
#define NODES (193 * 193)             // 37249
#define PH (NODES * 64)               // halves per packed plane
#define PB ((size_t)PH * 2)           // bytes per packed plane (4,767,872)
#define CONV_ELEMS (NODES * 16)       // (node,c) pairs per plane
#define NCB ((CONV_ELEMS + 255) / 256)  // convert blocks per plane

// ---- full-path workspace layout (bytes) ----
// qplanes : fp16 packed, 6*PB            @ 0            (28,607,232)
// hist    : int[4096]                    @ 6*PB
// offs    : int[4096]                    @ 6*PB + 16384
// key     : int[N]                       @ 6*PB + 32768
// idx_s   : int[N]                       @ ... + 4N
// pos_s   : float4[N]                    @ ... + 8N     (16B aligned)

__device__ __forceinline__ void pos_to_base(
    float4 p4, const float* cr, const float* res,
    int& bt, int& bx, int& by, int& bz,
    float& ft, float& fx, float& fy, float& fz, bool& inr)
{
    const float lo0 = cr[0], lo1 = cr[1], lo2 = cr[2], lo3 = cr[3];
    const float hi0 = cr[4], hi1 = cr[5], hi2 = cr[6], hi3 = cr[7];
    const float r0 = res[0], r1 = res[1], r2 = res[2], r3 = res[3];

    float pt = (p4.x - lo0) / (hi0 - lo0);
    float px = (p4.y - lo1) / (hi1 - lo1);
    float py = (p4.z - lo2) / (hi2 - lo2);
    float pz = (p4.w - lo3) / (hi3 - lo3);

    inr = (pt >= 0.f) && (pt < 1.f) && (px >= 0.f) && (px < 1.f)
       && (py >= 0.f) && (py < 1.f) && (pz >= 0.f) && (pz < 1.f);

    pt *= r0; px *= r1; py *= r2; pz *= r3;

    bt = min(max((int)floorf(pt), 0), (int)r0 - 1);
    bx = min(max((int)floorf(px), 0), (int)r1 - 1);
    by = min(max((int)floorf(py), 0), (int)r2 - 1);
    bz = min(max((int)floorf(pz), 0), (int)r3 - 1);

    ft = pt - (float)bt; fx = px - (float)bx;
    fy = py - (float)by; fz = pz - (float)bz;
}

__device__ __forceinline__ int morton4d(int a, int b, int c, int d) {
    int m = 0;
#pragma unroll
    for (int i = 0; i < 3; ++i) {
        m |= ((d >> i) & 1) << (4 * i + 0);
        m |= ((c >> i) & 1) << (4 * i + 1);
        m |= ((b >> i) & 1) << (4 * i + 2);
        m |= ((a >> i) & 1) << (4 * i + 3);
    }
    return m;
}

// ---- fused convert (f32 -> packed fp16) + histogram ----
__global__ __launch_bounds__(256) void k_convert_hist(
    const float* __restrict__ ptx, const float* __restrict__ pty,
    const float* __restrict__ ptz, const float* __restrict__ pxy,
    const float* __restrict__ pxz, const float* __restrict__ pyz,
    __half* __restrict__ qplanes,
    const float* __restrict__ pos, const float* __restrict__ cr,
    const float* __restrict__ res, int* __restrict__ key,
    int* __restrict__ hist, int N)
{
    const int b = blockIdx.x;
    if (b < 6 * NCB) {
        const int plane = b / NCB;
        const int idx = (b % NCB) * 256 + threadIdx.x;
        if (idx >= CONV_ELEMS) return;
        const float* src = plane == 0 ? ptx : plane == 1 ? pty : plane == 2 ? ptz
                         : plane == 3 ? pxy : plane == 4 ? pxz : pyz;
        const int c = idx & 15, node = idx >> 4;
        const int o = node * 16 + c;
        const float v0 = src[o];
        const float v1 = src[o + F_STRIDE];
        const float v2 = src[o + 2 * F_STRIDE];
        const float v3 = src[o + 3 * F_STRIDE];
        const __half2 h01 = __floats2half2_rn(v0, v1);
        const __half2 h23 = __floats2half2_rn(v2, v3);
        uint2 w;
        w.x = *(const unsigned*)&h01;
        w.y = *(const unsigned*)&h23;
        *(uint2*)(qplanes + (size_t)plane * PH + node * 64 + c * 4) = w;
    } else {
        const int i = (b - 6 * NCB) * 256 + threadIdx.x;
        if (i >= N) return;
        const float4 p4 = *reinterpret_cast<const float4*>(pos + (size_t)i * 4);
        int bt, bx, by, bz; float ft, fx, fy, fz; bool inr;
        pos_to_base(p4, cr, res, bt, bx, by, bz, ft, fx, fy, fz, inr);
        const int k = morton4d(bt / 24, bx / 24, by / 24, bz / 24);
        key[i] = k;
        atomicAdd(&hist[k], 1);
    }
}

__global__ __launch_bounds__(256) void k_scan(const int* __restrict__ hist,
                                              int* __restrict__ offs)
{
    __shared__ int part[256];
    const int t = threadIdx.x;
    int loc[16];
    int s = 0;
    const int base = t * 16;
#pragma unroll
    for (int j = 0; j < 16; ++j) { loc[j] = s; s += hist[base + j]; }
    part[t] = s;
    __syncthreads();
    for (int d = 1; d < 256; d <<= 1) {
        int v = (t >= d) ? part[t - d] : 0;
        __syncthreads();
        part[t] += v;
        __syncthreads();
    }
    const int excl = (t == 0) ? 0 : part[t - 1];
#pragma unroll
    for (int j = 0; j < 16; ++j) offs[base + j] = excl + loc[j];
}

__global__ __launch_bounds__(256) void k_scatter(
    const float* __restrict__ pos, const int* __restrict__ key,
    int* __restrict__ offs, float4* __restrict__ pos_s,
    int* __restrict__ idx_s, int N)
{
    const int i = blockIdx.x * 256 + threadIdx.x;
    if (i >= N) return;
    const int b = key[i];
    const int o = atomicAdd(&offs[b], 1);
    pos_s[o] = *reinterpret_cast<const float4*>(pos + (size_t)i * 4);
    idx_s[o] = i;
}

// accumulate w * (8 fp16 halves in one uint4) into af[8]
__device__ __forceinline__ void fma8(uint4 v, float w, float* af) {
    const unsigned u[4] = {v.x, v.y, v.z, v.w};
#pragma unroll
    for (int k = 0; k < 4; ++k) {
        const __half2 h = *(const __half2*)&u[k];
        const float2 f = __half22float2(h);
        af[2 * k]     += w * f.x;
        af[2 * k + 1] += w * f.y;
    }
}

// bilerp of one node-quad: p00 points at this lane's 16B (2c x 4f) chunk
__device__ __forceinline__ void bilerp8(const __half* __restrict__ p00,
                                        float fi, float fj, float* af)
{
    const uint4 v00 = *(const uint4*)p00;
    const uint4 v01 = *(const uint4*)(p00 + 64);
    const uint4 v10 = *(const uint4*)(p00 + 193 * 64);
    const uint4 v11 = *(const uint4*)(p00 + 193 * 64 + 64);
    const float w11 = fi * fj;
    const float w10 = fi - w11;
    const float w01 = fj - w11;
    const float w00 = 1.f - fi - fj + w11;
#pragma unroll
    for (int k = 0; k < 8; ++k) af[k] = 0.f;
    fma8(v00, w00, af);
    fma8(v01, w01, af);
    fma8(v10, w10, af);
    fma8(v11, w11, af);
}

__global__ __launch_bounds__(256) void fv4d_fp16(
    const float4* __restrict__ pos_s, const int* __restrict__ idx_s,
    const __half* __restrict__ qplanes, const float* __restrict__ cr,
    const float* __restrict__ res, float2* __restrict__ out, int N)
{
    // bijective XCD-chunked swizzle (m204)
    const int nwg = gridDim.x;
    const int q = nwg >> 3, r = nwg & 7;
    const int xcd = blockIdx.x & 7, jj = blockIdx.x >> 3;
    const int sb = (xcd < r ? xcd * (q + 1) : r * (q + 1) + (xcd - r) * q) + jj;

    const int n = sb * 32 + (threadIdx.x >> 3);  // 8 lanes per point
    const int q8 = threadIdx.x & 7;              // channel pair 0..7
    if (n >= N) return;

    const float4 p4 = pos_s[n];
    int bt, bx, by, bz; float ft, fx, fy, fz; bool inr;
    pos_to_base(p4, cr, res, bt, bx, by, bz, ft, fx, fy, fz, inr);

    const __half* qtx = qplanes;
    const __half* qty = qplanes + PH;
    const __half* qtz = qplanes + 2 * (size_t)PH;
    const __half* qxy = qplanes + 3 * (size_t)PH;
    const __half* qxz = qplanes + 4 * (size_t)PH;
    const __half* qyz = qplanes + 5 * (size_t)PH;
    const int co = q8 * 8;  // halves offset of this lane's 2-channel chunk

    float acc0 = 0.f, acc1 = 0.f;
    float af[8], bf[8];

    // pair 0: tx(t,x) * yz(y,z)
    bilerp8(qtx + (bt * 193 + bx) * 64 + co, ft, fx, af);
    bilerp8(qyz + (by * 193 + bz) * 64 + co, fy, fz, bf);
#pragma unroll
    for (int f = 0; f < 4; ++f) {
        acc0 += af[f] * bf[f];
        acc1 += af[4 + f] * bf[4 + f];
    }
    // pair 1: ty(t,y) * xz(x,z)
    bilerp8(qty + (bt * 193 + by) * 64 + co, ft, fy, af);
    bilerp8(qxz + (bx * 193 + bz) * 64 + co, fx, fz, bf);
#pragma unroll
    for (int f = 0; f < 4; ++f) {
        acc0 += af[f] * bf[f];
        acc1 += af[4 + f] * bf[4 + f];
    }
    // pair 2: tz(t,z) * xy(x,y)
    bilerp8(qtz + (bt * 193 + bz) * 64 + co, ft, fz, af);
    bilerp8(qxy + (bx * 193 + by) * 64 + co, fx, fy, bf);
#pragma unroll
    for (int f = 0; f < 4; ++f) {
        acc0 += af[f] * bf[f];
        acc1 += af[4 + f] * bf[4 + f];
    }

    float2 o;
    o.x = inr ? acc0 : 0.f;
    o.y = inr ? acc1 : 0.f;
    out[(size_t)idx_s[n] * 8 + q8] = o;
}

// ---- mid-tier fallback: f32 float4 sorted kernel ----
__device__ __forceinline__ float4 bil4(const float4* __restrict__ p, int o,
                                       float fi, float fj)
{
    const float4 v00 = p[o];
    const float4 v01 = p[o + 4];
    const float4 v10 = p[o + F4_ROW];
    const float4 v11 = p[o + F4_ROW + 4];
    float4 a, b, r;
    a.x = v00.x + fj * (v01.x - v00.x);
    a.y = v00.y + fj * (v01.y - v00.y);
    a.z = v00.z + fj * (v01.z - v00.z);
    a.w = v00.w + fj * (v01.w - v00.w);
    b.x = v10.x + fj * (v11.x - v10.x);
    b.y = v10.y + fj * (v11.y - v10.y);
    b.z = v10.z + fj * (v11.z - v10.z);
    b.w = v10.w + fj * (v11.w - v10.w);
    r.x = a.x + fi * (b.x - a.x);
    r.y = a.y + fi * (b.y - a.y);
    r.z = a.z + fi * (b.z - a.z);
    r.w = a.w + fi * (b.w - a.w);
    return r;
}

__global__ __launch_bounds__(256) void fv4d_sorted(
    const float4* __restrict__ pos_s, const int* __restrict__ idx_s,
    const float4* __restrict__ ptx, const float4* __restrict__ pty,
    const float4* __restrict__ ptz, const float4* __restrict__ pxy,
    const float4* __restrict__ pxz, const float4* __restrict__ pyz,
    const float* __restrict__ cr, const float* __restrict__ res,
    float4* __restrict__ out, int N)
{
    const int nwg = gridDim.x;
    const int q = nwg >> 3, r = nwg & 7;
    const int xcd = blockIdx.x & 7, jj = blockIdx.x >> 3;
    const int sb = (xcd < r ? xcd * (q + 1) : r * (q + 1) + (xcd - r) * q) + jj;

    const int n = sb * 64 + (threadIdx.x >> 2);
    const int q4 = threadIdx.x & 3;
    if (n >= N) return;

    const float4 p4 = pos_s[n];
    int bt, bx, by, bz; float ft, fx, fy, fz; bool inr;
    pos_to_base(p4, cr, res, bt, bx, by, bz, ft, fx, fy, fz, inr);

    const int otx = (bt * 193 + bx) * 4 + q4;
    const int oyz = (by * 193 + bz) * 4 + q4;
    const int oty = (bt * 193 + by) * 4 + q4;
    const int oxz = (bx * 193 + bz) * 4 + q4;
    const int otz = (bt * 193 + bz) * 4 + q4;
    const int oxy = (bx * 193 + by) * 4 + q4;

    float4 acc = make_float4(0.f, 0.f, 0.f, 0.f);
#pragma unroll
    for (int f = 0; f < 4; ++f) {
        const int fo = f * F4_F;
        const float4 atx = bil4(ptx, fo + otx, ft, fx);
        const float4 ayz = bil4(pyz, fo + oyz, fy, fz);
        const float4 aty = bil4(pty, fo + oty, ft, fy);
        const float4 axz = bil4(pxz, fo + oxz, fx, fz);
        const float4 atz = bil4(ptz, fo + otz, ft, fz);
        const float4 axy = bil4(pxy, fo + oxy, fx, fy);
        acc.x += atx.x * ayz.x + aty.x * axz.x + atz.x * axy.x;
        acc.y += atx.y * ayz.y + aty.y * axz.y + atz.y * axy.y;
        acc.z += atx.z * ayz.z + aty.z * axz.z + atz.z * axy.z;
        acc.w += atx.w * ayz.w + aty.w * axz.w + atz.w * axy.w;
    }

    if (!inr) acc = make_float4(0.f, 0.f, 0.f, 0.f);
    out[(size_t)idx_s[n] * 4 + q4] = acc;
}

__global__ __launch_bounds__(256) void k_hist(
    const float* __restrict__ pos, const float* __restrict__ cr,
    const float* __restrict__ res, int* __restrict__ key,
    int* __restrict__ hist, int N)
{
    const int i = blockIdx.x * 256 + threadIdx.x;
    if (i >= N) return;
    const float4 p4 = *reinterpret_cast<const float4*>(pos + (size_t)i * 4);
    int bt, bx, by, bz; float ft, fx, fy, fz; bool inr;
    pos_to_base(p4, cr, res, bt, bx, by, bz, ft, fx, fy, fz, inr);
    const int b = morton4d(bt / 24, bx / 24, by / 24, bz / 24);
    key[i] = b;
    atomicAdd(&hist[b], 1);
}

// bottom-tier fallback: plain scalar kernel
__global__ __launch_bounds__(256) void fv4d_plain(
    const float* __restrict__ pos,
    const float* __restrict__ ptx, const float* __restrict__ pty,
    const float* __restrict__ ptz, const float* __restrict__ pxy,
    const float* __restrict__ pxz, const float* __restrict__ pyz,
    const float* __restrict__ cr, const float* __restrict__ res,
    float* __restrict__ out, int N)
{
    const int g = blockIdx.x * 256 + threadIdx.x;
    const int n = g >> 4;
    const int c = g & 15;
    if (n >= N) return;
    const float4 p4 = *reinterpret_cast<const float4*>(pos + (size_t)n * 4);
    int bt, bx, by, bz; float ft, fx, fy, fz; bool inr;
    pos_to_base(p4, cr, res, bt, bx, by, bz, ft, fx, fy, fz, inr);
    const float gt = 1.f - ft, gx = 1.f - fx, gy = 1.f - fy, gz = 1.f - fz;
    const float wtx00 = gt * gx, wtx01 = gt * fx, wtx10 = ft * gx, wtx11 = ft * fx;
    const float wyz00 = gy * gz, wyz01 = gy * fz, wyz10 = fy * gz, wyz11 = fy * fz;
    const float wty00 = gt * gy, wty01 = gt * fy, wty10 = ft * gy, wty11 = ft * fy;
    const float wxz00 = gx * gz, wxz01 = gx * fz, wxz10 = fx * gz, wxz11 = fx * fz;
    const float wtz00 = gt * gz, wtz01 = gt * fz, wtz10 = ft * gz, wtz11 = ft * fz;
    const float wxy00 = gx * gy, wxy01 = gx * fy, wxy10 = fx * gy, wxy11 = fx * fy;
    const int otx = (bt * 193 + bx) * 16 + c;
    const int oyz = (by * 193 + bz) * 16 + c;
    const int oty = (bt * 193 + by) * 16 + c;
    const int oxz = (bx * 193 + bz) * 16 + c;
    const int otz = (bt * 193 + bz) * 16 + c;
    const int oxy = (bx * 193 + by) * 16 + c;
    float acc = 0.f;
#pragma unroll
    for (int f = 0; f < 4; ++f) {
        const int fo = f * F_STRIDE;
        acc += (ptx[fo + otx] * wtx00 + ptx[fo + otx + 16] * wtx01
              + ptx[fo + otx + ROW_STRIDE] * wtx10 + ptx[fo + otx + ROW_STRIDE + 16] * wtx11)
             * (pyz[fo + oyz] * wyz00 + pyz[fo + oyz + 16] * wyz01
              + pyz[fo + oyz + ROW_STRIDE] * wyz10 + pyz[fo + oyz + ROW_STRIDE + 16] * wyz11)
             + (pty[fo + oty] * wty00 + pty[fo + oty + 16] * wty01
              + pty[fo + oty + ROW_STRIDE] * wty10 + pty[fo + oty + ROW_STRIDE + 16] * wty11)
             * (pxz[fo + oxz] * wxz00 + pxz[fo + oxz + 16] * wxz01
              + pxz[fo + oxz + ROW_STRIDE] * wxz10 + pxz[fo + oxz + ROW_STRIDE + 16] * wxz11)
             + (ptz[fo + otz] * wtz00 + ptz[fo + otz + 16] * wtz01
              + ptz[fo + otz + ROW_STRIDE] * wtz10 + ptz[fo + otz + ROW_STRIDE + 16] * wtz11)
             * (pxy[fo + oxy] * wxy00 + pxy[fo + oxy + 16] * wxy01
              + pxy[fo + oxy + ROW_STRIDE] * wxy10 + pxy[fo + oxy + ROW_STRIDE + 16] * wxy11);
    }
    out[(size_t)n * 16 + c] = inr ? acc : 0.f;
}

extern "C" void kernel_launch(void* const* d_in, const int* in_sizes, int n_in,
                              void* d_out, int out_size, void* d_ws, size_t ws_size,
                              hipStream_t stream) {
    const float* pos = (const float*)d_in[0];
    const float* ptx = (const float*)d_in[1];
    const float* pty = (const float*)d_in[2];
    const float* ptz = (const float*)d_in[3];
    const float* pxy = (const float*)d_in[4];
    const float* pxz = (const float*)d_in[5];
    const float* pyz = (const float*)d_in[6];
    const float* cr  = (const float*)d_in[7];
    const float* res = (const float*)d_in[8];
    float* out = (float*)d_out;

    const int N = in_sizes[0] / 4;
    const int pb = (N + 255) / 256;

    const size_t QTOT = 6 * PB;
    const size_t full_need = QTOT + 32768 + (size_t)24 * N;
    const size_t sort_need = 32768 + (size_t)24 * N;

    if (ws_size >= full_need) {
        char* ws = (char*)d_ws;
        __half* qplanes = (__half*)ws;
        int*    hist    = (int*)(ws + QTOT);
        int*    offs    = (int*)(ws + QTOT + 16384);
        int*    key     = (int*)(ws + QTOT + 32768);
        int*    idx_s   = (int*)(ws + QTOT + 32768 + (size_t)4 * N);
        float4* pos_s   = (float4*)(ws + QTOT + 32768 + (size_t)8 * N);

        hipMemsetAsync(hist, 0, NBINS * sizeof(int), stream);
        k_convert_hist<<<6 * NCB + pb, 256, 0, stream>>>(
            ptx, pty, ptz, pxy, pxz, pyz, qplanes, pos, cr, res, key, hist, N);
        k_scan<<<1, 256, 0, stream>>>(hist, offs);
        k_scatter<<<pb, 256, 0, stream>>>(pos, key, offs, pos_s, idx_s, N);
        const int mainBlocks = (N + 31) / 32;  // 32 points/block, 8 lanes/point
        fv4d_fp16<<<mainBlocks, 256, 0, stream>>>(pos_s, idx_s, qplanes, cr, res,
                                                  (float2*)out, N);
    } else if (ws_size >= sort_need) {
        char* ws = (char*)d_ws;
        int*    hist  = (int*)(ws);
        int*    offs  = (int*)(ws + 16384);
        int*    key   = (int*)(ws + 32768);
        int*    idx_s = (int*)(ws + 32768 + (size_t)4 * N);
        float4* pos_s = (float4*)(ws + 32768 + (size_t)8 * N);

        hipMemsetAsync(hist, 0, NBINS * sizeof(int), stream);
        k_hist<<<pb, 256, 0, stream>>>(pos, cr, res, key, hist, N);
        k_scan<<<1, 256, 0, stream>>>(hist, offs);
        k_scatter<<<pb, 256, 0, stream>>>(pos, key, offs, pos_s, idx_s, N);
        const int mainBlocks = (N + 63) / 64;
        fv4d_sorted<<<mainBlocks, 256, 0, stream>>>(
            pos_s, idx_s,
            (const float4*)ptx, (const float4*)pty, (const float4*)ptz,
            (const float4*)pxy, (const float4*)pxz, (const float4*)pyz,
            cr, res, (float4*)out, N);
    } else {
        const int blocks = (N * 16 + 255) / 256;
        fv4d_plain<<<blocks, 256, 0, stream>>>(pos, ptx, pty, ptz, pxy, pxz, pyz,
                                               cr, res, out, N);
    }
}